// Round 20
// baseline (1429.298 us; speedup 1.0000x reference)
//
#include <hip/hip_runtime.h>
#include <hip/hip_bf16.h>
#include <math.h>

#define B_ 8
#define S_ 8192
#define D_ 2048
#define L_ 512
#define H_ 16
#define DH_ 128
#define TOPK_ 2048
#define EXTCAP 24
#define SLOTS (TOPK_ + 64)     // 2112
#define RCAPW 524288           // wide (3-term midpoint-adjacent) flags
#define NCAP 65536             // narrow (exact) risky records
#define DELTAW 2.5e-5f         // wide band on 3-term value (~9 sigma of 2.8e-6)
#define DELTAN 6e-6            // narrow band on exact value (hedge trigger)
#define BFCAP 2048             // per-block LDS flag buffer entries
#define QCH 32
#define QCHD (D_ / QCH)
#define PCH 8
#define PCHD (D_ / PCH)
#define VCH 8
#define VCHK (SLOTS / VCH)

typedef __attribute__((ext_vector_type(8))) short short8;
typedef __attribute__((ext_vector_type(4))) float f32x4;

// fp8 e4m3fn RNE quantize from float (matches ml_dtypes astype from f32)
__device__ __forceinline__ float q8(float x) {
  float ax = fabsf(x);
  if (!(ax >= 0.015625f)) return rintf(x * 512.0f) * 0.001953125f;
  int ee; frexpf(ax, &ee);
  float step = ldexpf(1.0f, ee - 4);
  return rintf(ldexpf(x, 4 - ee)) * step;
}

// float quantize + midpoint distance (wide flagging on 3-term value)
__device__ __forceinline__ float q8_midf(float v, float* dist) {
  float av = fabsf(v);
  float step, u;
  if (!(av >= 0.015625f)) { step = 0.001953125f; u = v * 512.0f; }
  else { int ee; frexpf(av, &ee); step = ldexpf(1.0f, ee - 4); u = ldexpf(v, 4 - ee); }
  float m = rintf(u);
  *dist = (0.5f - fabsf(u - m)) * step;
  return m * step;
}

// double quantize + midpoint analysis (exact fixup + hedge detection)
__device__ __forceinline__ float q8d_mid(double v, float* qflip, double* dist) {
  double av = fabs(v);
  double step, u;
  if (!(av >= 0.015625)) { step = 0.001953125; u = v * 512.0; }
  else { int ee; frexp(av, &ee); step = ldexp(1.0, ee - 4); u = ldexp(v, 4 - ee); }
  double m = rint(u);
  double f = u - m;
  *dist = (0.5 - fabs(f)) * step;
  double sgn = (f >= 0.0) ? 1.0 : -1.0;
  *qflip = (float)((m + sgn) * step);
  return (float)(m * step);
}

__device__ __forceinline__ float b2f(unsigned u) {
  return __uint_as_float(u << 16);
}
__device__ __forceinline__ ushort bfr(float x) {
  unsigned u = __float_as_uint(x);
  return (ushort)((u + 0x7FFFu + ((u >> 16) & 1u)) >> 16);
}
__device__ __forceinline__ float uf(ushort h) {
  return __uint_as_float(((unsigned)h) << 16);
}
// 2-way bf16 split (3-term product needs only h,m planes)
__device__ __forceinline__ void split2(float x, ushort& h, ushort& m) {
  h = bfr(x); m = bfr(x - uf(h));
}

__device__ __forceinline__ f32x4 mfma16(short8 a, short8 b, f32x4 c) {
  return __builtin_amdgcn_mfma_f32_16x16x32_bf16(a, b, c, 0, 0, 0);
}

#if __has_builtin(__builtin_amdgcn_global_load_lds)
#define HAS_GLL 1
__device__ __forceinline__ void gload_lds16(const void* g, void* l) {
  __builtin_amdgcn_global_load_lds(
      (const __attribute__((address_space(1))) void*)g,
      (__attribute__((address_space(3))) void*)l, 16, 0, 0);
}
#else
#define HAS_GLL 0
#endif

__global__ __launch_bounds__(256) void zero_kernel(
    int* flag, int* wideCnt, int* narrowCnt, int* extraCnt, int* cntI2O) {
  int i = blockIdx.x * 256 + threadIdx.x;
  if (i < B_ * S_) flag[i] = 0;
  if (i == 0) { *wideCnt = 0; *narrowCnt = 0; }
  if (i < B_) { extraCnt[i] = 0; cntI2O[i] = 0; }
}

// Pre-split Wkv_down into 2 bf16 planes (h,m) in LDS-ready layout:
// Wsp[T][kblk(64)][kb(4)][col(1024)][8]
__global__ __launch_bounds__(256) void wsplit_kernel(
    const float* __restrict__ W, ushort* __restrict__ Wsp) {
  const int c = blockIdx.x * 256 + threadIdx.x;
  const int kblk = blockIdx.y;
  float xe[32];
#pragma unroll
  for (int e = 0; e < 32; ++e) xe[e] = W[(long)(kblk * 32 + e) * 1024 + c];
#pragma unroll
  for (int kb = 0; kb < 4; ++kb) {
    ushort Hh[8], Mm[8];
#pragma unroll
    for (int e = 0; e < 8; ++e) split2(xe[kb * 8 + e], Hh[e], Mm[e]);
    *(short8*)&Wsp[((((long)0 * 64 + kblk) * 4 + kb) * 1024 + c) * 8] = *(short8*)Hh;
    *(short8*)&Wsp[((((long)1 * 64 + kblk) * 4 + kb) * 1024 + c) * 8] = *(short8*)Mm;
  }
}

// One-shot: WT[l][k] = Wkv_down[k][l] for l<512
__global__ __launch_bounds__(256) void wtrans_kernel(
    const float* __restrict__ W, float* __restrict__ WT) {
  const int l = blockIdx.y;
  const int k = blockIdx.x * 256 + threadIdx.x;
  WT[(long)l * D_ + k] = W[(long)k * 1024 + l];
}

// One-shot: Wq8[d][l] = q8(Wq_down[d][l]) as bf16 bits
__global__ __launch_bounds__(256) void wq8_kernel(
    const float* __restrict__ Wqd, ushort* __restrict__ Wq8) {
  const long i = ((long)blockIdx.x * 256 + threadIdx.x) * 4;
  float4 v = *(const float4*)(Wqd + i);
  ushort4 o;
  o.x = (ushort)(__float_as_uint(q8(v.x)) >> 16);
  o.y = (ushort)(__float_as_uint(q8(v.y)) >> 16);
  o.z = (ushort)(__float_as_uint(q8(v.z)) >> 16);
  o.w = (ushort)(__float_as_uint(q8(v.w)) >> 16);
  *(ushort4*)(Wq8 + i) = o;
}

#define AS_IDX(T, kb, r) ((((T)*8 + (kb)) * 128 + (r)) * 8)
#define BS_IDX(T, kb, n) ((((T)*8 + (kb)) * 128 + (n)) * 8)

// MFMA GEMM, 3-term bf16 split (hh,hm,mh), 2 planes, fp32 accumulate.
// BK=64: two 32-k blocks per barrier pair -> 96 MFMAs/iteration (amortizes
// the fixed barrier+staging cost; per-C-element order unchanged ->
// bit-identical). LDS 72KB -> 2 blocks/CU.
template <bool QUANT>
__global__ __launch_bounds__(256, 2) void gemm_mfma(
    const float* __restrict__ X, const ushort* __restrict__ Wsp, int colbase,
    int mbase, const float* __restrict__ bias, float* __restrict__ C,
    ushort* __restrict__ Cq8, const int* __restrict__ rowmap,
    int* __restrict__ wideList, int* __restrict__ wideCnt) {
  __shared__ __align__(16) ushort As[2 * 8 * 128 * 8];   // 32 KB
  __shared__ __align__(16) ushort Bs[2 * 8 * 128 * 8];   // 32 KB
  __shared__ int blkFlags[BFCAP];                        // 8 KB
  __shared__ int blkCnt, blkBase;
  const int tid = threadIdx.x;
  const int cpx = gridDim.x >> 3;
  const int lid = (blockIdx.x & 7) * cpx + (blockIdx.x >> 3);
  const int m0 = (mbase + (lid >> 2)) * 128;
  const int n0 = (lid & 3) * 128;
  const int ar_ = tid >> 1;
  const int kh = (tid & 1) << 5;          // 0 or 32
  const int arow = rowmap ? rowmap[m0 + ar_] : (m0 + ar_);
  const float* aptr = X + (long)arow * D_ + kh;
  const int cb = colbase + n0;

  if (QUANT && tid == 0) blkCnt = 0;

  f32x4 acc[4][4];
#pragma unroll
  for (int i = 0; i < 4; ++i)
#pragma unroll
    for (int j = 0; j < 4; ++j) acc[i][j] = (f32x4){0.f, 0.f, 0.f, 0.f};

  const int w = tid >> 6, lane = tid & 63;
  const int wm = (w & 1) * 64, wn = (w >> 1) * 64;
  const int lr = lane & 15, lq = lane >> 4;

  float4 v[8];
#pragma unroll
  for (int i = 0; i < 8; ++i) v[i] = *(const float4*)(aptr + i * 4);

  for (int k0 = 0; k0 < D_; k0 += 64) {
    const int kblk2 = k0 >> 5;            // first 32-k block index of the pair
    __syncthreads();
    // B: 2 planes x 8 kb8 = 16 slices x 2KB = 32 x 1KB chunks; 8 per wave
#pragma unroll
    for (int i = 0; i < 8; ++i) {
      const int c = w * 8 + i;            // 0..31
      const int s = c >> 1, half = c & 1; // slice 0..15
      const int T = s >> 3, kb8 = s & 7;
      const int kblk = kblk2 + (kb8 >> 2), kb4 = kb8 & 3;
      const ushort* g = Wsp + ((((long)T * 64 + kblk) * 4 + kb4) * 1024 +
                               (long)cb + half * 64 + lane) * 8;
#if HAS_GLL
      gload_lds16(g, &Bs[((T * 8 + kb8) * 128 + half * 64) * 8]);
#else
      *(short8*)&Bs[((T * 8 + kb8) * 128 + half * 64 + lane) * 8] = *(const short8*)g;
#endif
    }
    // A: split2 current 32 regs & write (row ar_, k = kh..kh+31 -> 4 kb groups)
    {
      const int kb0 = (tid & 1) * 4;
#pragma unroll
      for (int j8 = 0; j8 < 4; ++j8) {
        float xe[8] = {v[j8 * 2].x, v[j8 * 2].y, v[j8 * 2].z, v[j8 * 2].w,
                       v[j8 * 2 + 1].x, v[j8 * 2 + 1].y, v[j8 * 2 + 1].z, v[j8 * 2 + 1].w};
        ushort Hh[8], Mm[8];
#pragma unroll
        for (int e = 0; e < 8; ++e) split2(xe[e], Hh[e], Mm[e]);
        *(short8*)&As[AS_IDX(0, kb0 + j8, ar_)] = *(short8*)Hh;
        *(short8*)&As[AS_IDX(1, kb0 + j8, ar_)] = *(short8*)Mm;
      }
    }
    // A prefetch for next iteration
    if (k0 + 64 < D_) {
#pragma unroll
      for (int i = 0; i < 8; ++i)
        v[i] = *(const float4*)(aptr + k0 + 64 + i * 4);
    }
    __syncthreads();   // drains ds_writes AND global_load_lds

    // two 32-k MFMA steps; per-element term order: hh, hm, mh (k ascending)
#pragma unroll
    for (int s = 0; s < 2; ++s) {
      const int kb = s * 4 + lq;
      short8 af0[4], af1[4];
#pragma unroll
      for (int mf = 0; mf < 4; ++mf) {
        af0[mf] = *(const short8*)&As[AS_IDX(0, kb, wm + mf * 16 + lr)];
        af1[mf] = *(const short8*)&As[AS_IDX(1, kb, wm + mf * 16 + lr)];
      }
#pragma unroll
      for (int nf = 0; nf < 4; ++nf) {
        short8 bh = *(const short8*)&Bs[BS_IDX(0, kb, wn + nf * 16 + lr)];
        short8 bm = *(const short8*)&Bs[BS_IDX(1, kb, wn + nf * 16 + lr)];
#pragma unroll
        for (int mf = 0; mf < 4; ++mf) {
          f32x4 c = acc[mf][nf];
          c = mfma16(af0[mf], bh, c);   // hh
          c = mfma16(af0[mf], bm, c);   // hm
          c = mfma16(af1[mf], bh, c);   // mh
          acc[mf][nf] = c;
        }
      }
    }
  }

  // epilogue: D layout col = lane&15, row = (lane>>4)*4 + i
#pragma unroll
  for (int nf = 0; nf < 4; ++nf) {
    const int ng = n0 + wn + nf * 16 + lr;
    const float bb = bias[ng];
#pragma unroll
    for (int mf = 0; mf < 4; ++mf) {
      const int mg = m0 + wm + mf * 16 + lq * 4;
#pragma unroll
      for (int i = 0; i < 4; ++i) {
        float vv = acc[mf][nf][i] + bb;
        const long crow = (long)(mg + i);
        C[crow * L_ + ng] = vv;
        if (QUANT) {
          float dist;
          float q = q8_midf(vv, &dist);
          Cq8[crow * L_ + ng] = (ushort)(__float_as_uint(q) >> 16);
          if (dist < DELTAW) {
            int li = atomicAdd(&blkCnt, 1);      // LDS atomic: fast, per-CU
            int rec = ((int)crow << 9) | ng;
            if (li < BFCAP) blkFlags[li] = rec;
            else {                               // overflow (essentially never)
              int gi = atomicAdd(wideCnt, 1);
              if (gi < RCAPW) wideList[gi] = rec;
            }
          }
        }
      }
    }
  }
  if (QUANT) {
    __syncthreads();
    if (tid == 0) blkBase = atomicAdd(wideCnt, min(blkCnt, BFCAP));
    __syncthreads();
    const int nfl = min(blkCnt, BFCAP);
    for (int i2 = tid; i2 < nfl; i2 += 256) {
      int gi = blkBase + i2;
      if (gi < RCAPW) wideList[gi] = blkFlags[i2];
    }
  }
}

// Exact fixup: recompute flagged cells in f64, overwrite Kq8, emit narrow records
__global__ __launch_bounds__(256) void fixup_kernel(
    const int* __restrict__ wideList, const int* __restrict__ wideCnt,
    const float* __restrict__ x, const float* __restrict__ WT,
    const float* __restrict__ bkvd, ushort* __restrict__ Kq8,
    int2* __restrict__ narrowList, int* __restrict__ narrowCnt) {
  const int n = min(*wideCnt, RCAPW);
  const int lane = threadIdx.x & 63;
  const int wstride = gridDim.x * 4;
  for (int idx = blockIdx.x * 4 + (threadIdx.x >> 6); idx < n; idx += wstride) {
    const int packed = wideList[idx];
    const int row = packed >> 9;
    const int l = packed & 511;
    const float* xr = x + (long)row * D_;
    const float* wr = WT + (long)l * D_;
    double acc = 0.0;
    for (int k = lane; k < D_; k += 64)
      acc += (double)xr[k] * (double)wr[k];
#pragma unroll
    for (int off = 32; off >= 1; off >>= 1) acc += __shfl_xor(acc, off, 64);
    if (lane == 0) {
      double v = acc + (double)bkvd[l];
      float qflip; double dist;
      float q = q8d_mid(v, &qflip, &dist);
      Kq8[(long)row * L_ + l] = (ushort)(__float_as_uint(q) >> 16);
      if (dist < DELTAN) {
        int i2 = atomicAdd(narrowCnt, 1);
        if (i2 < NCAP) {
          unsigned qbits = __float_as_uint(qflip) >> 16;
          narrowList[i2] = make_int2(row, (l << 16) | (int)qbits);
        }
      }
    }
  }
}

// qidx partials (selection path)
__global__ __launch_bounds__(256) void qidx_part(
    const float* __restrict__ x, const ushort* __restrict__ Wq8,
    double* __restrict__ qpart) {
  __shared__ float qs[QCHD];
  const int b = blockIdx.y;
  const int c = blockIdx.x;
  const int t = threadIdx.x;
  const int d0 = c * QCHD;
  const float* xr = x + ((long)b * S_ + (S_ - 1)) * D_ + d0;
  if (t < QCHD) qs[t] = q8(xr[t]);
  __syncthreads();
  double a0 = 0.0, a1 = 0.0;
  const ushort* wr = Wq8 + (long)d0 * L_;
  for (int dd = 0; dd < QCHD; ++dd) {
    const double qv = (double)qs[dd];
    a0 += qv * (double)b2f((unsigned)wr[dd * L_ + t]);
    a1 += qv * (double)b2f((unsigned)wr[dd * L_ + t + 256]);
  }
  double* qp = qpart + ((long)b * QCH + c) * L_;
  qp[t] = a0;
  qp[t + 256] = a1;
}

__global__ __launch_bounds__(256) void qidx_reduce(
    const double* __restrict__ qpart, const float* __restrict__ bqd,
    float* __restrict__ qidx) {
  const int i = blockIdx.x * 256 + threadIdx.x;
  const int b = i >> 9, l = i & 511;
  double acc = 0.0;
  for (int c = 0; c < QCH; ++c)
    acc += qpart[((long)b * QCH + c) * L_ + l];
  qidx[i] = (float)(acc + (double)q8(bqd[l]));
}

// scores (f32, wave per row)
__global__ __launch_bounds__(256) void scores_kernel(
    const ushort* __restrict__ Kq8, const float* __restrict__ qidx,
    float* __restrict__ scores) {
  __shared__ float qs[L_];
  const int m0 = blockIdx.x * 4;
  const int b = m0 >> 13;
  const int t = threadIdx.x;
  if (t < 128) ((float4*)qs)[t] = ((const float4*)(qidx + b * L_))[t];
  __syncthreads();
  const int wave = t >> 6, lane = t & 63;
  const long m = m0 + wave;
  uint4 rv = *(const uint4*)(Kq8 + m * L_ + lane * 8);
  const float* q = qs + lane * 8;
  float p = 0.f;
  p = fmaf(q[0], b2f(rv.x & 0xffffu), p);
  p = fmaf(q[1], b2f(rv.x >> 16), p);
  p = fmaf(q[2], b2f(rv.y & 0xffffu), p);
  p = fmaf(q[3], b2f(rv.y >> 16), p);
  p = fmaf(q[4], b2f(rv.z & 0xffffu), p);
  p = fmaf(q[5], b2f(rv.z >> 16), p);
  p = fmaf(q[6], b2f(rv.w & 0xffffu), p);
  p = fmaf(q[7], b2f(rv.w >> 16), p);
#pragma unroll
  for (int off = 32; off >= 1; off >>= 1) p += __shfl_xor(p, off, 64);
  if (lane == 0) scores[m] = (p > 0.f) ? p : 0.f;
}

// deterministic top-k (register-resident)
__global__ __launch_bounds__(256) void topk_kernel(
    const float* __restrict__ scores, int* __restrict__ rowmap,
    float* __restrict__ vstarF) {
  __shared__ int red[256];
  __shared__ int cgt_sh;
  const int b = blockIdx.x, t = threadIdx.x;
  const int wave = t >> 6, lane = t & 63;
  const int c0 = t * 32;
  unsigned sv[32];
#pragma unroll
  for (int i = 0; i < 32; ++i)
    sv[i] = __float_as_uint(scores[(long)b * S_ + c0 + i]);
  unsigned prefix = 0u;
  for (int bit = 30; bit >= 0; --bit) {
    unsigned cand = prefix | (1u << bit);
    int c = 0;
#pragma unroll
    for (int i = 0; i < 32; ++i) c += (sv[i] >= cand) ? 1 : 0;
#pragma unroll
    for (int off = 32; off >= 1; off >>= 1) c += __shfl_xor(c, off, 64);
    if (lane == 0) red[wave] = c;
    __syncthreads();
    int total = red[0] + red[1] + red[2] + red[3];
    if (total >= TOPK_) prefix = cand;
    __syncthreads();
  }
  const unsigned vstar = prefix;
  if (t == 0) vstarF[b] = __uint_as_float(vstar);
  int cnt = 0;
#pragma unroll
  for (int i = 0; i < 32; ++i) cnt += (sv[i] > vstar) ? 1 : 0;
  red[t] = cnt;
  __syncthreads();
  if (t == 0) {
    int run = 0;
    for (int i = 0; i < 256; ++i) { int c = red[i]; red[i] = run; run += c; }
    cgt_sh = run;
  }
  __syncthreads();
  int pos = red[t];
#pragma unroll
  for (int i = 0; i < 32; ++i)
    if (sv[i] > vstar) rowmap[b * TOPK_ + pos++] = b * S_ + c0 + i;
  __syncthreads();
  int tcnt = 0;
#pragma unroll
  for (int i = 0; i < 32; ++i) tcnt += (sv[i] == vstar) ? 1 : 0;
  red[t] = tcnt;
  __syncthreads();
  if (t == 0) {
    int run = 0;
    for (int i = 0; i < 256; ++i) { int c = red[i]; red[i] = run; run += c; }
  }
  __syncthreads();
  int tpos = cgt_sh + red[t];
#pragma unroll
  for (int i = 0; i < 32; ++i)
    if (sv[i] == vstar) {
      if (tpos < TOPK_) rowmap[b * TOPK_ + tpos] = b * S_ + c0 + i;
      ++tpos;
    }
}

// For each narrow risky cell: does flipping change IN/OUT status?
__global__ __launch_bounds__(256) void risky_eval(
    const int2* __restrict__ list, const int* __restrict__ narrowCnt,
    const ushort* __restrict__ Kq8, const float* __restrict__ qidx,
    const float* __restrict__ scores, const float* __restrict__ vstarF,
    int* __restrict__ flag, int* __restrict__ extraRows,
    int* __restrict__ extraCnt, int* __restrict__ cntI2O) {
  int i = blockIdx.x * 256 + threadIdx.x;
  int n = min(*narrowCnt, NCAP);
  if (i >= n) return;
  int row = list[i].x;
  int l = list[i].y >> 16;
  float qflip = b2f((unsigned)(list[i].y & 0xffff));
  int b = row >> 13;
  float qorig = b2f((unsigned)Kq8[(long)row * L_ + l]);
  float shift = qidx[b * L_ + l] * (qflip - qorig);
  float s = scores[row];
  float vs = vstarF[b];
  bool in0 = (s >= vs);
  bool in1 = (s + shift >= vs);
  if (in0 != in1) {
    if (atomicCAS(&flag[row], 0, 1) == 0) {
      if (in0) {
        atomicAdd(&cntI2O[b], 1);
      } else {
        int e = atomicAdd(&extraCnt[b], 1);
        if (e < EXTCAP) extraRows[b * EXTCAP + e] = row;
      }
    }
  }
}

// hedge counterparties
__global__ __launch_bounds__(256) void counterparty_kernel(
    const float* __restrict__ scores, const int* __restrict__ rowmap,
    const float* __restrict__ vstarF, int* __restrict__ flag,
    int* __restrict__ extraRows, int* __restrict__ extraCnt,
    const int* __restrict__ cntI2O) {
  __shared__ float bv[256];
  __shared__ int bi[256];
  const int b = blockIdx.x, t = threadIdx.x;
  const float vs = vstarF[b];
  const int nA = min(extraCnt[b], EXTCAP);
  const int nD = min(cntI2O[b], EXTCAP);
  for (int pass = 0; pass < nA; ++pass) {
    float best = 3.4e38f; int besti = -1;
    for (int k = t; k < TOPK_; k += 256) {
      int r = rowmap[b * TOPK_ + k];
      if (!flag[r]) { float s = scores[r]; if (s < best) { best = s; besti = r; } }
    }
    bv[t] = best; bi[t] = besti; __syncthreads();
    for (int off = 128; off > 0; off >>= 1) {
      if (t < off && bv[t + off] < bv[t]) { bv[t] = bv[t + off]; bi[t] = bi[t + off]; }
      __syncthreads();
    }
    if (t == 0 && bi[0] >= 0) flag[bi[0]] = 1;
    __syncthreads();
  }
  for (int pass = 0; pass < nD; ++pass) {
    float best = -3.4e38f; int besti = -1;
    for (int s0 = t; s0 < S_; s0 += 256) {
      int r = b * S_ + s0;
      float s = scores[r];
      if (s < vs && !flag[r] && s > best) { best = s; besti = r; }
    }
    bv[t] = best; bi[t] = besti; __syncthreads();
    for (int off = 128; off > 0; off >>= 1) {
      if (t < off && bv[t + off] > bv[t]) { bv[t] = bv[t + off]; bi[t] = bi[t + off]; }
      __syncthreads();
    }
    if (t == 0 && bi[0] >= 0) {
      flag[bi[0]] = 1;
      int e = extraCnt[b];
      if (e < EXTCAP) { extraRows[b * EXTCAP + e] = bi[0]; extraCnt[b] = e + 1; }
    }
    __syncthreads();
  }
}

// rowmapExt + multExt
__global__ __launch_bounds__(256) void buildext_kernel(
    const int* __restrict__ rowmap, const int* __restrict__ extraRows,
    const int* __restrict__ extraCnt, const int* __restrict__ flag,
    int* __restrict__ rowmapExt, float* __restrict__ multExt) {
  const int b = blockIdx.y;
  const int k = blockIdx.x * 256 + threadIdx.x;
  if (k >= SLOTS) return;
  const int tot = min(extraCnt[b], EXTCAP);
  int row; float m;
  if (k < TOPK_) { row = rowmap[b * TOPK_ + k]; m = flag[row] ? 0.5f : 1.0f; }
  else if (k - TOPK_ < tot) { row = extraRows[b * EXTCAP + (k - TOPK_)]; m = 0.5f; }
  else { row = b * S_; m = 0.0f; }
  rowmapExt[b * SLOTS + k] = row;
  multExt[b * SLOTS + k] = m;
}

// value-path kernels
__global__ __launch_bounds__(128) void qproj_part(
    const float* __restrict__ x, const float* __restrict__ Wq,
    float* __restrict__ ppart) {
  __shared__ float xs[PCHD];
  const int b = blockIdx.y, c = blockIdx.z, t = threadIdx.x;
  const int d0 = c * PCHD;
  const float* xr = x + ((long)b * S_ + (S_ - 1)) * D_ + d0;
  xs[t] = xr[t]; xs[t + 128] = xr[t + 128];
  __syncthreads();
  const int n = blockIdx.x * 128 + t;
  float acc = 0.f;
  for (int dd = 0; dd < PCHD; ++dd)
    acc = fmaf(xs[dd], Wq[(long)(d0 + dd) * D_ + n], acc);
  ppart[((long)c * B_ + b) * D_ + n] = acc;
}

__global__ __launch_bounds__(256) void qproj_reduce(
    const float* __restrict__ ppart, const float* __restrict__ bq,
    float* __restrict__ q) {
  const int i = blockIdx.x * 256 + threadIdx.x;
  const int b = i >> 11, n = i & (D_ - 1);
  float acc = 0.f;
  for (int c = 0; c < PCH; ++c)
    acc += ppart[((long)c * B_ + b) * D_ + n];
  q[i] = acc + bq[n];
}

__global__ __launch_bounds__(256) void qt_kernel(
    const float* __restrict__ q, const float* __restrict__ Wkvu,
    const float* __restrict__ bkvu, float* __restrict__ qt,
    float* __restrict__ blog) {
  __shared__ float qh[DH_];
  __shared__ float red[DH_];
  const int h = blockIdx.x, b = blockIdx.y, t = threadIdx.x;
  if (t < DH_) qh[t] = q[b * D_ + h * DH_ + t];
  __syncthreads();
  for (int l = t; l < L_; l += 256) {
    const float* wr = Wkvu + (long)l * 4096 + h * DH_;
    float acc = 0.f;
    for (int d = 0; d < DH_; d += 4) {
      float4 w4 = *(const float4*)(wr + d);
      acc = fmaf(qh[d], w4.x, acc);
      acc = fmaf(qh[d + 1], w4.y, acc);
      acc = fmaf(qh[d + 2], w4.z, acc);
      acc = fmaf(qh[d + 3], w4.w, acc);
    }
    qt[((long)b * H_ + h) * L_ + l] = acc;
  }
  if (t < DH_) red[t] = qh[t] * bkvu[h * DH_ + t];
  __syncthreads();
  if (t == 0) {
    float s = 0.f;
    for (int i = 0; i < DH_; ++i) s += red[i];
    blog[b * H_ + h] = s;
  }
}

__global__ __launch_bounds__(256) void logits_kernel(
    const float* __restrict__ Kd, const int* __restrict__ rowmapExt,
    const float* __restrict__ qt, const float* __restrict__ blog,
    float* __restrict__ logits) {
  const int b = blockIdx.y;
  const int k = blockIdx.x * 16 + (threadIdx.x >> 4);
  const int h = threadIdx.x & 15;
  const float* kr = Kd + (long)rowmapExt[b * SLOTS + k] * L_;
  const float* qr = qt + ((long)b * H_ + h) * L_;
  float acc = 0.f;
  for (int l = 0; l < L_; l += 4) {
    float4 kv = *(const float4*)(kr + l);
    acc = fmaf(qr[l], kv.x, acc);
    acc = fmaf(qr[l + 1], kv.y, acc);
    acc = fmaf(qr[l + 2], kv.z, acc);
    acc = fmaf(qr[l + 3], kv.w, acc);
  }
  logits[((long)b * H_ + h) * SLOTS + k] =
      (acc + blog[b * H_ + h]) * 0.088388347648318447f;
}

__global__ __launch_bounds__(256) void softmax_kernel(
    float* __restrict__ logits, const float* __restrict__ multExt) {
  __shared__ float redf[4];
  __shared__ double redd[4];
  const int bh = blockIdx.x;
  const int b = bh >> 4;
  float* row = logits + (long)bh * SLOTS;
  const float* mult = multExt + b * SLOTS;
  const int t = threadIdx.x;
  const int wave = t >> 6, lane = t & 63;
  float m = -3.4e38f;
  for (int i = t; i < SLOTS; i += 256) m = fmaxf(m, row[i]);
#pragma unroll
  for (int off = 32; off >= 1; off >>= 1) m = fmaxf(m, __shfl_xor(m, off, 64));
  if (lane == 0) redf[wave] = m;
  __syncthreads();
  m = fmaxf(fmaxf(redf[0], redf[1]), fmaxf(redf[2], redf[3]));
  double s = 0.0;
  for (int i = t; i < SLOTS; i += 256) {
    float e = expf(row[i] - m) * mult[i];
    row[i] = e;
    s += (double)e;
  }
#pragma unroll
  for (int off = 32; off >= 1; off >>= 1) s += __shfl_xor(s, off, 64);
  if (lane == 0) redd[wave] = s;
  __syncthreads();
  const float inv = (float)(1.0 / (redd[0] + redd[1] + redd[2] + redd[3]));
  for (int i = t; i < SLOTS; i += 256) row[i] *= inv;
}

__global__ __launch_bounds__(256) void vt_part(
    const float* __restrict__ Vsel, const float* __restrict__ attn,
    float* __restrict__ vpart) {
  const int b = blockIdx.y, c = blockIdx.z;
  const int t = threadIdx.x;
  const int l = blockIdx.x * 64 + (t & 63);
  const int hg = t >> 6;
  float acc[4] = {0.f, 0.f, 0.f, 0.f};
  const float* ar = attn + (long)b * H_ * SLOTS;
  const int k0 = c * VCHK, k1 = k0 + VCHK;
  for (int k = k0; k < k1; ++k) {
    float v = Vsel[((long)b * SLOTS + k) * L_ + l];
#pragma unroll
    for (int a = 0; a < 4; ++a)
      acc[a] = fmaf(ar[(hg * 4 + a) * SLOTS + k], v, acc[a]);
  }
#pragma unroll
  for (int a = 0; a < 4; ++a)
    vpart[(((long)c * B_ + b) * H_ + hg * 4 + a) * L_ + l] = acc[a];
}

__global__ __launch_bounds__(256) void vt_reduce(
    const float* __restrict__ vpart, float* __restrict__ vt) {
  const int i = blockIdx.x * 256 + threadIdx.x;
  float acc = 0.f;
  for (int c = 0; c < VCH; ++c)
    acc += vpart[(long)c * (B_ * H_ * L_) + i];
  vt[i] = acc;
}

__global__ __launch_bounds__(512) void oproj_kernel(
    const float* __restrict__ vt, const float* __restrict__ Wkvu,
    const float* __restrict__ bkvu, float* __restrict__ o) {
  __shared__ float vs[L_];
  __shared__ float part[4][DH_];
  const int h = blockIdx.x, b = blockIdx.y, t = threadIdx.x;
  if (t < 128)
    ((float4*)vs)[t] = ((const float4*)(vt + ((long)b * H_ + h) * L_))[t];
  __syncthreads();
  const int lc = t >> 7;
  const int ct = t & 127;
  const int col = h * DH_ + ct;
  float acc = 0.f;
  const int l0 = lc * 128;
  for (int l = l0; l < l0 + 128; ++l)
    acc = fmaf(vs[l], Wkvu[(long)l * 4096 + 2048 + col], acc);
  part[lc][ct] = acc;
  __syncthreads();
  if (lc == 0)
    o[b * D_ + col] = ((part[0][ct] + part[1][ct]) + (part[2][ct] + part[3][ct]))
                      + bkvu[2048 + col];
}

__global__ __launch_bounds__(128) void out_part(
    const float* __restrict__ o, const float* __restrict__ Wout,
    float* __restrict__ opart) {
  __shared__ float os[PCHD];
  const int b = blockIdx.y, c = blockIdx.z, t = threadIdx.x;
  const int d0 = c * PCHD;
  const float* orr = o + (long)b * D_ + d0;
  os[t] = orr[t]; os[t + 128] = orr[t + 128];
  __syncthreads();
  const int n = blockIdx.x * 128 + t;
  float acc = 0.f;
  for (int dd = 0; dd < PCHD; ++dd)
    acc = fmaf(os[dd], Wout[(long)(d0 + dd) * D_ + n], acc);
  opart[((long)c * B_ + b) * D_ + n] = acc;
}

__global__ __launch_bounds__(256) void out_reduce(
    const float* __restrict__ opart, const float* __restrict__ bout,
    float* __restrict__ out) {
  const int i = blockIdx.x * 256 + threadIdx.x;
  const int b = i >> 11, n = i & (D_ - 1);
  float acc = 0.f;
  for (int c = 0; c < PCH; ++c)
    acc += opart[((long)c * B_ + b) * D_ + n];
  out[i] = acc + bout[n];
}

extern "C" void kernel_launch(void* const* d_in, const int* in_sizes, int n_in,
                              void* d_out, int out_size, void* d_ws, size_t ws_size,
                              hipStream_t stream) {
  const float* x    = (const float*)d_in[0];
  const float* Wq   = (const float*)d_in[1];
  const float* bq   = (const float*)d_in[2];
  const float* Wkvd = (const float*)d_in[3];
  const float* bkvd = (const float*)d_in[4];
  const float* Wqd  = (const float*)d_in[5];
  const float* bqd  = (const float*)d_in[6];
  const float* Wkvu = (const float*)d_in[7];
  const float* bkvu = (const float*)d_in[8];
  const float* Wo   = (const float*)d_in[9];
  const float* bo   = (const float*)d_in[10];
  float* out = (float*)d_out;

  char* p = (char*)d_ws;
  auto alloc = [&](size_t bytes) {
    char* r = p;
    p += (bytes + 255) & ~(size_t)255;
    return r;
  };
  float*  Kd       = (float*)alloc((size_t)B_ * S_ * L_ * 4);       // 134.2 MB
  ushort* Kq8      = (ushort*)alloc((size_t)B_ * S_ * L_ * 2);      // 67.1 MB
  float*  Vsel     = (float*)alloc((size_t)B_ * SLOTS * L_ * 4);    // 34.6 MB
  ushort* Wsp      = (ushort*)alloc((size_t)2 * 64 * 4 * 1024 * 8 * 2);  // 8.4 MB
  float*  WT       = (float*)alloc((size_t)L_ * D_ * 4);            // 4 MB
  ushort* Wq8      = (ushort*)alloc((size_t)D_ * L_ * 2);           // 2 MB
  double* qpart    = (double*)alloc((size_t)B_ * QCH * L_ * 8);     // 1 MB
  float*  ppart    = (float*)alloc((size_t)PCH * B_ * D_ * 4);
  float*  opart    = (float*)alloc((size_t)PCH * B_ * D_ * 4);
  float*  vpart    = (float*)alloc((size_t)VCH * B_ * H_ * L_ * 4);
  float*  scores   = (float*)alloc((size_t)B_ * S_ * 4);
  float*  qidx     = (float*)alloc((size_t)B_ * L_ * 4);
  int*    rowmap   = (int*)alloc((size_t)B_ * TOPK_ * 4);
  int*    rowmapE  = (int*)alloc((size_t)B_ * SLOTS * 4);
  float*  multE    = (float*)alloc((size_t)B_ * SLOTS * 4);
  float*  vstarF   = (float*)alloc((size_t)B_ * 4);
  int*    wideL    = (int*)alloc((size_t)RCAPW * 4);                // 2 MB
  int2*   narrowL  = (int2*)alloc((size_t)NCAP * 8);                // 0.5 MB
  int*    wideCnt  = (int*)alloc(256);
  int*    narrowCnt= (int*)alloc(256);
  int*    flagArr  = (int*)alloc((size_t)B_ * S_ * 4);
  int*    extraR   = (int*)alloc((size_t)B_ * EXTCAP * 4);
  int*    extraCnt = (int*)alloc((size_t)B_ * 4);
  int*    cntI2O   = (int*)alloc((size_t)B_ * 4);
  float*  qv       = (float*)alloc((size_t)B_ * D_ * 4);
  float*  qt       = (float*)alloc((size_t)B_ * H_ * L_ * 4);
  float*  blog     = (float*)alloc((size_t)B_ * H_ * 4);
  float*  logits   = (float*)alloc((size_t)B_ * H_ * SLOTS * 4);
  float*  vt       = (float*)alloc((size_t)B_ * H_ * L_ * 4);
  float*  ov       = (float*)alloc((size_t)B_ * D_ * 4);
  (void)ws_size; (void)in_sizes; (void)n_in; (void)out_size;

  zero_kernel<<<(B_ * S_ + 255) / 256, 256, 0, stream>>>(flagArr, wideCnt, narrowCnt, extraCnt, cntI2O);
  // one-shot weight preprocessing
  wsplit_kernel<<<dim3(4, 64), 256, 0, stream>>>(Wkvd, Wsp);
  wtrans_kernel<<<dim3(D_ / 256, L_), 256, 0, stream>>>(Wkvd, WT);
  wq8_kernel<<<(D_ * L_ / 4) / 256, 256, 0, stream>>>(Wqd, Wq8);
  // K_down via 3-term bf16-split MFMA, BK=64, single merged 2048-block dispatch
  gemm_mfma<true><<<2048, 256, 0, stream>>>(
      x, Wsp, 0, 0, bkvd, Kd, Kq8, nullptr, wideL, wideCnt);
  // exact fixup of midpoint-adjacent cells -> Kq8 exact-grade + narrow records
  fixup_kernel<<<8192, 256, 0, stream>>>(wideL, wideCnt, x, WT, bkvd, Kq8, narrowL, narrowCnt);
  // selection path
  qidx_part<<<dim3(QCH, B_), 256, 0, stream>>>(x, Wq8, qpart);
  qidx_reduce<<<(B_ * L_) / 256, 256, 0, stream>>>(qpart, bqd, qidx);
  scores_kernel<<<(B_ * S_) / 4, 256, 0, stream>>>(Kq8, qidx, scores);
  topk_kernel<<<B_, 256, 0, stream>>>(scores, rowmap, vstarF);
  risky_eval<<<NCAP / 256, 256, 0, stream>>>(narrowL, narrowCnt, Kq8, qidx, scores, vstarF,
                                             flagArr, extraR, extraCnt, cntI2O);
  counterparty_kernel<<<B_, 256, 0, stream>>>(scores, rowmap, vstarF, flagArr, extraR, extraCnt, cntI2O);
  buildext_kernel<<<dim3((SLOTS + 255) / 256, B_), 256, 0, stream>>>(rowmap, extraR, extraCnt, flagArr, rowmapE, multE);
  // V_down at selected+hedged rows (3-term, value-grade), 528 blocks
  gemm_mfma<false><<<528, 256, 0, stream>>>(
      x, Wsp, 512, 0, bkvd + 512, Vsel, nullptr, rowmapE, nullptr, nullptr);
  // attention (up-projections folded), parallelized value path
  qproj_part<<<dim3(D_ / 128, B_, PCH), 128, 0, stream>>>(x, Wq, ppart);
  qproj_reduce<<<(B_ * D_) / 256, 256, 0, stream>>>(ppart, bq, qv);
  qt_kernel<<<dim3(H_, B_), 256, 0, stream>>>(qv, Wkvu, bkvu, qt, blog);
  logits_kernel<<<dim3(SLOTS / 16, B_), 256, 0, stream>>>(Kd, rowmapE, qt, blog, logits);
  softmax_kernel<<<B_ * H_, 256, 0, stream>>>(logits, multE);
  vt_part<<<dim3(L_ / 64, B_, VCH), 256, 0, stream>>>(Vsel, logits, vpart);
  vt_reduce<<<(B_ * H_ * L_) / 256, 256, 0, stream>>>(vpart, vt);
  oproj_kernel<<<dim3(H_, B_), 512, 0, stream>>>(vt, Wkvu, bkvu, ov);
  out_part<<<dim3(D_ / 128, B_, PCH), 128, 0, stream>>>(ov, Wo, opart);
  out_reduce<<<(B_ * D_) / 256, 256, 0, stream>>>(opart, bo, out);
}

// Round 21
// 1410.576 us; speedup vs baseline: 1.0133x; 1.0133x over previous
//
#include <hip/hip_runtime.h>
#include <hip/hip_bf16.h>
#include <math.h>

#define B_ 8
#define S_ 8192
#define D_ 2048
#define L_ 512
#define H_ 16
#define DH_ 128
#define TOPK_ 2048
#define EXTCAP 24
#define SLOTS (TOPK_ + 64)     // 2112
#define RCAPW 524288           // wide (3-term midpoint-adjacent) flags
#define NCAP 65536             // narrow (exact) risky records
#define DELTAW 2.5e-5f         // wide band on 3-term value (~9 sigma of 2.8e-6)
#define DELTAN 6e-6            // narrow band on exact value (hedge trigger)
#define BFCAP 4096             // per-block LDS flag buffer entries
#define QCH 32
#define QCHD (D_ / QCH)
#define PCH 8
#define PCHD (D_ / PCH)
#define VCH 8
#define VCHK (SLOTS / VCH)

typedef __attribute__((ext_vector_type(8))) short short8;
typedef __attribute__((ext_vector_type(4))) float f32x4;

// fp8 e4m3fn RNE quantize from float (matches ml_dtypes astype from f32)
__device__ __forceinline__ float q8(float x) {
  float ax = fabsf(x);
  if (!(ax >= 0.015625f)) return rintf(x * 512.0f) * 0.001953125f;
  int ee; frexpf(ax, &ee);
  float step = ldexpf(1.0f, ee - 4);
  return rintf(ldexpf(x, 4 - ee)) * step;
}

// float quantize + midpoint distance (wide flagging on 3-term value)
__device__ __forceinline__ float q8_midf(float v, float* dist) {
  float av = fabsf(v);
  float step, u;
  if (!(av >= 0.015625f)) { step = 0.001953125f; u = v * 512.0f; }
  else { int ee; frexpf(av, &ee); step = ldexpf(1.0f, ee - 4); u = ldexpf(v, 4 - ee); }
  float m = rintf(u);
  *dist = (0.5f - fabsf(u - m)) * step;
  return m * step;
}

// double quantize + midpoint analysis (exact fixup + hedge detection)
__device__ __forceinline__ float q8d_mid(double v, float* qflip, double* dist) {
  double av = fabs(v);
  double step, u;
  if (!(av >= 0.015625)) { step = 0.001953125; u = v * 512.0; }
  else { int ee; frexp(av, &ee); step = ldexp(1.0, ee - 4); u = ldexp(v, 4 - ee); }
  double m = rint(u);
  double f = u - m;
  *dist = (0.5 - fabs(f)) * step;
  double sgn = (f >= 0.0) ? 1.0 : -1.0;
  *qflip = (float)((m + sgn) * step);
  return (float)(m * step);
}

__device__ __forceinline__ float b2f(unsigned u) {
  return __uint_as_float(u << 16);
}
__device__ __forceinline__ ushort bfr(float x) {
  unsigned u = __float_as_uint(x);
  return (ushort)((u + 0x7FFFu + ((u >> 16) & 1u)) >> 16);
}
__device__ __forceinline__ float uf(ushort h) {
  return __uint_as_float(((unsigned)h) << 16);
}
// 2-way bf16 split (3-term product needs only h,m planes)
__device__ __forceinline__ void split2(float x, ushort& h, ushort& m) {
  h = bfr(x); m = bfr(x - uf(h));
}

__device__ __forceinline__ f32x4 mfma16(short8 a, short8 b, f32x4 c) {
  return __builtin_amdgcn_mfma_f32_16x16x32_bf16(a, b, c, 0, 0, 0);
}

#if __has_builtin(__builtin_amdgcn_global_load_lds)
#define HAS_GLL 1
__device__ __forceinline__ void gload_lds16(const void* g, void* l) {
  __builtin_amdgcn_global_load_lds(
      (const __attribute__((address_space(1))) void*)g,
      (__attribute__((address_space(3))) void*)l, 16, 0, 0);
}
#else
#define HAS_GLL 0
#endif

__global__ __launch_bounds__(256) void zero_kernel(
    int* flag, int* wideCnt, int* narrowCnt, int* extraCnt, int* cntI2O) {
  int i = blockIdx.x * 256 + threadIdx.x;
  if (i < B_ * S_) flag[i] = 0;
  if (i == 0) { *wideCnt = 0; *narrowCnt = 0; }
  if (i < B_) { extraCnt[i] = 0; cntI2O[i] = 0; }
}

// Pre-split Wkv_down into 2 bf16 planes (h,m) in LDS-ready layout:
// Wsp[T][kblk(64)][kb(4)][col(1024)][8]
__global__ __launch_bounds__(256) void wsplit_kernel(
    const float* __restrict__ W, ushort* __restrict__ Wsp) {
  const int c = blockIdx.x * 256 + threadIdx.x;
  const int kblk = blockIdx.y;
  float xe[32];
#pragma unroll
  for (int e = 0; e < 32; ++e) xe[e] = W[(long)(kblk * 32 + e) * 1024 + c];
#pragma unroll
  for (int kb = 0; kb < 4; ++kb) {
    ushort Hh[8], Mm[8];
#pragma unroll
    for (int e = 0; e < 8; ++e) split2(xe[kb * 8 + e], Hh[e], Mm[e]);
    *(short8*)&Wsp[((((long)0 * 64 + kblk) * 4 + kb) * 1024 + c) * 8] = *(short8*)Hh;
    *(short8*)&Wsp[((((long)1 * 64 + kblk) * 4 + kb) * 1024 + c) * 8] = *(short8*)Mm;
  }
}

// One-shot: WT[l][k] = Wkv_down[k][l] for l<512
__global__ __launch_bounds__(256) void wtrans_kernel(
    const float* __restrict__ W, float* __restrict__ WT) {
  const int l = blockIdx.y;
  const int k = blockIdx.x * 256 + threadIdx.x;
  WT[(long)l * D_ + k] = W[(long)k * 1024 + l];
}

// One-shot: Wq8[d][l] = q8(Wq_down[d][l]) as bf16 bits
__global__ __launch_bounds__(256) void wq8_kernel(
    const float* __restrict__ Wqd, ushort* __restrict__ Wq8) {
  const long i = ((long)blockIdx.x * 256 + threadIdx.x) * 4;
  float4 v = *(const float4*)(Wqd + i);
  ushort4 o;
  o.x = (ushort)(__float_as_uint(q8(v.x)) >> 16);
  o.y = (ushort)(__float_as_uint(q8(v.y)) >> 16);
  o.z = (ushort)(__float_as_uint(q8(v.z)) >> 16);
  o.w = (ushort)(__float_as_uint(q8(v.w)) >> 16);
  *(ushort4*)(Wq8 + i) = o;
}

#define AS_IDX(T, kb, r) ((((T)*4 + (kb)) * 128 + (r)) * 8)
#define BS_IDX(T, kb, n) ((((T)*4 + (kb)) * 128 + (n)) * 8)

// MFMA GEMM, 3-term bf16 split (hh,hm,mh), 2 planes, fp32 accumulate.
// QUANT epilogue: flags buffered in LDS; ONE ranged global atomic per block.
template <bool QUANT>
__global__ __launch_bounds__(256, 2) void gemm_mfma(
    const float* __restrict__ X, const ushort* __restrict__ Wsp, int colbase,
    int mbase, const float* __restrict__ bias, float* __restrict__ C,
    ushort* __restrict__ Cq8, const int* __restrict__ rowmap,
    int* __restrict__ wideList, int* __restrict__ wideCnt) {
  __shared__ __align__(16) ushort As[2 * 4 * 128 * 8];   // 16 KB
  __shared__ __align__(16) ushort Bs[2 * 4 * 128 * 8];   // 16 KB
  __shared__ int blkFlags[BFCAP];                        // 16 KB
  __shared__ int blkCnt, blkBase;
  const int tid = threadIdx.x;
  const int cpx = gridDim.x >> 3;
  const int lid = (blockIdx.x & 7) * cpx + (blockIdx.x >> 3);
  const int m0 = (mbase + (lid >> 2)) * 128;
  const int n0 = (lid & 3) * 128;
  const int ar_ = tid >> 1;
  const int kh = (tid & 1) << 4;
  const int arow = rowmap ? rowmap[m0 + ar_] : (m0 + ar_);
  const float* aptr = X + (long)arow * D_ + kh;
  const int cb = colbase + n0;

  if (QUANT && tid == 0) blkCnt = 0;

  f32x4 acc[4][4];
#pragma unroll
  for (int i = 0; i < 4; ++i)
#pragma unroll
    for (int j = 0; j < 4; ++j) acc[i][j] = (f32x4){0.f, 0.f, 0.f, 0.f};

  const int w = tid >> 6, lane = tid & 63;
  const int wm = (w & 1) * 64, wn = (w >> 1) * 64;
  const int lr = lane & 15, lq = lane >> 4;

  float4 v0 = *(const float4*)(aptr + 0);
  float4 v1 = *(const float4*)(aptr + 4);
  float4 v2 = *(const float4*)(aptr + 8);
  float4 v3 = *(const float4*)(aptr + 12);

  for (int k0 = 0; k0 < D_; k0 += 32) {
    const int kblk = k0 >> 5;
    __syncthreads();
    // B: 2 planes x 4 kb x 2 halves = 16 x 1KB chunks; 4 per wave
#pragma unroll
    for (int i = 0; i < 4; ++i) {
      const int c = w * 4 + i;
      const int s = c >> 1, half = c & 1;
      const int T = s >> 2, kb = s & 3;
      const ushort* g = Wsp + ((((long)T * 64 + kblk) * 4 + kb) * 1024 +
                               (long)cb + half * 64 + lane) * 8;
#if HAS_GLL
      gload_lds16(g, &Bs[(s * 128 + half * 64) * 8]);
#else
      *(short8*)&Bs[(s * 128 + half * 64 + lane) * 8] = *(const short8*)g;
#endif
    }
    // A: split2 current regs & write
    {
      float xe[16] = {v0.x, v0.y, v0.z, v0.w, v1.x, v1.y, v1.z, v1.w,
                      v2.x, v2.y, v2.z, v2.w, v3.x, v3.y, v3.z, v3.w};
      const int kb0 = (tid & 1) * 2;
#pragma unroll
      for (int j8 = 0; j8 < 2; ++j8) {
        ushort Hh[8], Mm[8];
#pragma unroll
        for (int e = 0; e < 8; ++e) split2(xe[j8 * 8 + e], Hh[e], Mm[e]);
        *(short8*)&As[AS_IDX(0, kb0 + j8, ar_)] = *(short8*)Hh;
        *(short8*)&As[AS_IDX(1, kb0 + j8, ar_)] = *(short8*)Mm;
      }
    }
    if (k0 + 32 < D_) {
      v0 = *(const float4*)(aptr + k0 + 32);
      v1 = *(const float4*)(aptr + k0 + 36);
      v2 = *(const float4*)(aptr + k0 + 40);
      v3 = *(const float4*)(aptr + k0 + 44);
    }
    __syncthreads();

    short8 af[4][2];
#pragma unroll
    for (int mf = 0; mf < 4; ++mf) {
      af[mf][0] = *(const short8*)&As[AS_IDX(0, lq, wm + mf * 16 + lr)];
      af[mf][1] = *(const short8*)&As[AS_IDX(1, lq, wm + mf * 16 + lr)];
    }
#pragma unroll
    for (int nf = 0; nf < 4; ++nf) {
      short8 bh = *(const short8*)&Bs[BS_IDX(0, lq, wn + nf * 16 + lr)];
      short8 bm = *(const short8*)&Bs[BS_IDX(1, lq, wn + nf * 16 + lr)];
#pragma unroll
      for (int mf = 0; mf < 4; ++mf) {
        f32x4 c = acc[mf][nf];
        c = mfma16(af[mf][0], bh, c);   // hh
        c = mfma16(af[mf][0], bm, c);   // hm
        c = mfma16(af[mf][1], bh, c);   // mh
        acc[mf][nf] = c;
      }
    }
  }

  // epilogue: D layout col = lane&15, row = (lane>>4)*4 + i
#pragma unroll
  for (int nf = 0; nf < 4; ++nf) {
    const int ng = n0 + wn + nf * 16 + lr;
    const float bb = bias[ng];
#pragma unroll
    for (int mf = 0; mf < 4; ++mf) {
      const int mg = m0 + wm + mf * 16 + lq * 4;
#pragma unroll
      for (int i = 0; i < 4; ++i) {
        float v = acc[mf][nf][i] + bb;
        const long crow = (long)(mg + i);
        C[crow * L_ + ng] = v;
        if (QUANT) {
          float dist;
          float q = q8_midf(v, &dist);
          Cq8[crow * L_ + ng] = (ushort)(__float_as_uint(q) >> 16);
          if (dist < DELTAW) {
            int li = atomicAdd(&blkCnt, 1);      // LDS atomic: fast, per-CU
            int rec = ((int)crow << 9) | ng;
            if (li < BFCAP) blkFlags[li] = rec;
            else {                               // overflow (essentially never)
              int gi = atomicAdd(wideCnt, 1);
              if (gi < RCAPW) wideList[gi] = rec;
            }
          }
        }
      }
    }
  }
  if (QUANT) {
    __syncthreads();
    if (tid == 0) blkBase = atomicAdd(wideCnt, min(blkCnt, BFCAP));
    __syncthreads();
    const int nfl = min(blkCnt, BFCAP);
    for (int i2 = tid; i2 < nfl; i2 += 256) {
      int gi = blkBase + i2;
      if (gi < RCAPW) wideList[gi] = blkFlags[i2];
    }
  }
}

// Exact fixup: recompute flagged cells in f64, overwrite Kq8, emit narrow records
__global__ __launch_bounds__(256) void fixup_kernel(
    const int* __restrict__ wideList, const int* __restrict__ wideCnt,
    const float* __restrict__ x, const float* __restrict__ WT,
    const float* __restrict__ bkvd, ushort* __restrict__ Kq8,
    int2* __restrict__ narrowList, int* __restrict__ narrowCnt) {
  const int n = min(*wideCnt, RCAPW);
  const int lane = threadIdx.x & 63;
  const int wstride = gridDim.x * 4;
  for (int idx = blockIdx.x * 4 + (threadIdx.x >> 6); idx < n; idx += wstride) {
    const int packed = wideList[idx];
    const int row = packed >> 9;
    const int l = packed & 511;
    const float* xr = x + (long)row * D_;
    const float* wr = WT + (long)l * D_;
    double acc = 0.0;
    for (int k = lane; k < D_; k += 64)
      acc += (double)xr[k] * (double)wr[k];
#pragma unroll
    for (int off = 32; off >= 1; off >>= 1) acc += __shfl_xor(acc, off, 64);
    if (lane == 0) {
      double v = acc + (double)bkvd[l];
      float qflip; double dist;
      float q = q8d_mid(v, &qflip, &dist);
      Kq8[(long)row * L_ + l] = (ushort)(__float_as_uint(q) >> 16);
      if (dist < DELTAN) {
        int i2 = atomicAdd(narrowCnt, 1);
        if (i2 < NCAP) {
          unsigned qbits = __float_as_uint(qflip) >> 16;
          narrowList[i2] = make_int2(row, (l << 16) | (int)qbits);
        }
      }
    }
  }
}

// qidx partials (selection path)
__global__ __launch_bounds__(256) void qidx_part(
    const float* __restrict__ x, const ushort* __restrict__ Wq8,
    double* __restrict__ qpart) {
  __shared__ float qs[QCHD];
  const int b = blockIdx.y;
  const int c = blockIdx.x;
  const int t = threadIdx.x;
  const int d0 = c * QCHD;
  const float* xr = x + ((long)b * S_ + (S_ - 1)) * D_ + d0;
  if (t < QCHD) qs[t] = q8(xr[t]);
  __syncthreads();
  double a0 = 0.0, a1 = 0.0;
  const ushort* wr = Wq8 + (long)d0 * L_;
  for (int dd = 0; dd < QCHD; ++dd) {
    const double qv = (double)qs[dd];
    a0 += qv * (double)b2f((unsigned)wr[dd * L_ + t]);
    a1 += qv * (double)b2f((unsigned)wr[dd * L_ + t + 256]);
  }
  double* qp = qpart + ((long)b * QCH + c) * L_;
  qp[t] = a0;
  qp[t + 256] = a1;
}

__global__ __launch_bounds__(256) void qidx_reduce(
    const double* __restrict__ qpart, const float* __restrict__ bqd,
    float* __restrict__ qidx) {
  const int i = blockIdx.x * 256 + threadIdx.x;
  const int b = i >> 9, l = i & 511;
  double acc = 0.0;
  for (int c = 0; c < QCH; ++c)
    acc += qpart[((long)b * QCH + c) * L_ + l];
  qidx[i] = (float)(acc + (double)q8(bqd[l]));
}

// scores (f32, wave per row)
__global__ __launch_bounds__(256) void scores_kernel(
    const ushort* __restrict__ Kq8, const float* __restrict__ qidx,
    float* __restrict__ scores) {
  __shared__ float qs[L_];
  const int m0 = blockIdx.x * 4;
  const int b = m0 >> 13;
  const int t = threadIdx.x;
  if (t < 128) ((float4*)qs)[t] = ((const float4*)(qidx + b * L_))[t];
  __syncthreads();
  const int wave = t >> 6, lane = t & 63;
  const long m = m0 + wave;
  uint4 rv = *(const uint4*)(Kq8 + m * L_ + lane * 8);
  const float* q = qs + lane * 8;
  float p = 0.f;
  p = fmaf(q[0], b2f(rv.x & 0xffffu), p);
  p = fmaf(q[1], b2f(rv.x >> 16), p);
  p = fmaf(q[2], b2f(rv.y & 0xffffu), p);
  p = fmaf(q[3], b2f(rv.y >> 16), p);
  p = fmaf(q[4], b2f(rv.z & 0xffffu), p);
  p = fmaf(q[5], b2f(rv.z >> 16), p);
  p = fmaf(q[6], b2f(rv.w & 0xffffu), p);
  p = fmaf(q[7], b2f(rv.w >> 16), p);
#pragma unroll
  for (int off = 32; off >= 1; off >>= 1) p += __shfl_xor(p, off, 64);
  if (lane == 0) scores[m] = (p > 0.f) ? p : 0.f;
}

// deterministic top-k (register-resident)
__global__ __launch_bounds__(256) void topk_kernel(
    const float* __restrict__ scores, int* __restrict__ rowmap,
    float* __restrict__ vstarF) {
  __shared__ int red[256];
  __shared__ int cgt_sh;
  const int b = blockIdx.x, t = threadIdx.x;
  const int wave = t >> 6, lane = t & 63;
  const int c0 = t * 32;
  unsigned sv[32];
#pragma unroll
  for (int i = 0; i < 32; ++i)
    sv[i] = __float_as_uint(scores[(long)b * S_ + c0 + i]);
  unsigned prefix = 0u;
  for (int bit = 30; bit >= 0; --bit) {
    unsigned cand = prefix | (1u << bit);
    int c = 0;
#pragma unroll
    for (int i = 0; i < 32; ++i) c += (sv[i] >= cand) ? 1 : 0;
#pragma unroll
    for (int off = 32; off >= 1; off >>= 1) c += __shfl_xor(c, off, 64);
    if (lane == 0) red[wave] = c;
    __syncthreads();
    int total = red[0] + red[1] + red[2] + red[3];
    if (total >= TOPK_) prefix = cand;
    __syncthreads();
  }
  const unsigned vstar = prefix;
  if (t == 0) vstarF[b] = __uint_as_float(vstar);
  int cnt = 0;
#pragma unroll
  for (int i = 0; i < 32; ++i) cnt += (sv[i] > vstar) ? 1 : 0;
  red[t] = cnt;
  __syncthreads();
  if (t == 0) {
    int run = 0;
    for (int i = 0; i < 256; ++i) { int c = red[i]; red[i] = run; run += c; }
    cgt_sh = run;
  }
  __syncthreads();
  int pos = red[t];
#pragma unroll
  for (int i = 0; i < 32; ++i)
    if (sv[i] > vstar) rowmap[b * TOPK_ + pos++] = b * S_ + c0 + i;
  __syncthreads();
  int tcnt = 0;
#pragma unroll
  for (int i = 0; i < 32; ++i) tcnt += (sv[i] == vstar) ? 1 : 0;
  red[t] = tcnt;
  __syncthreads();
  if (t == 0) {
    int run = 0;
    for (int i = 0; i < 256; ++i) { int c = red[i]; red[i] = run; run += c; }
  }
  __syncthreads();
  int tpos = cgt_sh + red[t];
#pragma unroll
  for (int i = 0; i < 32; ++i)
    if (sv[i] == vstar) {
      if (tpos < TOPK_) rowmap[b * TOPK_ + tpos] = b * S_ + c0 + i;
      ++tpos;
    }
}

// For each narrow risky cell: does flipping change IN/OUT status?
__global__ __launch_bounds__(256) void risky_eval(
    const int2* __restrict__ list, const int* __restrict__ narrowCnt,
    const ushort* __restrict__ Kq8, const float* __restrict__ qidx,
    const float* __restrict__ scores, const float* __restrict__ vstarF,
    int* __restrict__ flag, int* __restrict__ extraRows,
    int* __restrict__ extraCnt, int* __restrict__ cntI2O) {
  int i = blockIdx.x * 256 + threadIdx.x;
  int n = min(*narrowCnt, NCAP);
  if (i >= n) return;
  int row = list[i].x;
  int l = list[i].y >> 16;
  float qflip = b2f((unsigned)(list[i].y & 0xffff));
  int b = row >> 13;
  float qorig = b2f((unsigned)Kq8[(long)row * L_ + l]);
  float shift = qidx[b * L_ + l] * (qflip - qorig);
  float s = scores[row];
  float vs = vstarF[b];
  bool in0 = (s >= vs);
  bool in1 = (s + shift >= vs);
  if (in0 != in1) {
    if (atomicCAS(&flag[row], 0, 1) == 0) {
      if (in0) {
        atomicAdd(&cntI2O[b], 1);
      } else {
        int e = atomicAdd(&extraCnt[b], 1);
        if (e < EXTCAP) extraRows[b * EXTCAP + e] = row;
      }
    }
  }
}

// hedge counterparties
__global__ __launch_bounds__(256) void counterparty_kernel(
    const float* __restrict__ scores, const int* __restrict__ rowmap,
    const float* __restrict__ vstarF, int* __restrict__ flag,
    int* __restrict__ extraRows, int* __restrict__ extraCnt,
    const int* __restrict__ cntI2O) {
  __shared__ float bv[256];
  __shared__ int bi[256];
  const int b = blockIdx.x, t = threadIdx.x;
  const float vs = vstarF[b];
  const int nA = min(extraCnt[b], EXTCAP);
  const int nD = min(cntI2O[b], EXTCAP);
  for (int pass = 0; pass < nA; ++pass) {
    float best = 3.4e38f; int besti = -1;
    for (int k = t; k < TOPK_; k += 256) {
      int r = rowmap[b * TOPK_ + k];
      if (!flag[r]) { float s = scores[r]; if (s < best) { best = s; besti = r; } }
    }
    bv[t] = best; bi[t] = besti; __syncthreads();
    for (int off = 128; off > 0; off >>= 1) {
      if (t < off && bv[t + off] < bv[t]) { bv[t] = bv[t + off]; bi[t] = bi[t + off]; }
      __syncthreads();
    }
    if (t == 0 && bi[0] >= 0) flag[bi[0]] = 1;
    __syncthreads();
  }
  for (int pass = 0; pass < nD; ++pass) {
    float best = -3.4e38f; int besti = -1;
    for (int s0 = t; s0 < S_; s0 += 256) {
      int r = b * S_ + s0;
      float s = scores[r];
      if (s < vs && !flag[r] && s > best) { best = s; besti = r; }
    }
    bv[t] = best; bi[t] = besti; __syncthreads();
    for (int off = 128; off > 0; off >>= 1) {
      if (t < off && bv[t + off] > bv[t]) { bv[t] = bv[t + off]; bi[t] = bi[t + off]; }
      __syncthreads();
    }
    if (t == 0 && bi[0] >= 0) {
      flag[bi[0]] = 1;
      int e = extraCnt[b];
      if (e < EXTCAP) { extraRows[b * EXTCAP + e] = bi[0]; extraCnt[b] = e + 1; }
    }
    __syncthreads();
  }
}

// rowmapExt + multExt
__global__ __launch_bounds__(256) void buildext_kernel(
    const int* __restrict__ rowmap, const int* __restrict__ extraRows,
    const int* __restrict__ extraCnt, const int* __restrict__ flag,
    int* __restrict__ rowmapExt, float* __restrict__ multExt) {
  const int b = blockIdx.y;
  const int k = blockIdx.x * 256 + threadIdx.x;
  if (k >= SLOTS) return;
  const int tot = min(extraCnt[b], EXTCAP);
  int row; float m;
  if (k < TOPK_) { row = rowmap[b * TOPK_ + k]; m = flag[row] ? 0.5f : 1.0f; }
  else if (k - TOPK_ < tot) { row = extraRows[b * EXTCAP + (k - TOPK_)]; m = 0.5f; }
  else { row = b * S_; m = 0.0f; }
  rowmapExt[b * SLOTS + k] = row;
  multExt[b * SLOTS + k] = m;
}

// value-path kernels
__global__ __launch_bounds__(128) void qproj_part(
    const float* __restrict__ x, const float* __restrict__ Wq,
    float* __restrict__ ppart) {
  __shared__ float xs[PCHD];
  const int b = blockIdx.y, c = blockIdx.z, t = threadIdx.x;
  const int d0 = c * PCHD;
  const float* xr = x + ((long)b * S_ + (S_ - 1)) * D_ + d0;
  xs[t] = xr[t]; xs[t + 128] = xr[t + 128];
  __syncthreads();
  const int n = blockIdx.x * 128 + t;
  float acc = 0.f;
  for (int dd = 0; dd < PCHD; ++dd)
    acc = fmaf(xs[dd], Wq[(long)(d0 + dd) * D_ + n], acc);
  ppart[((long)c * B_ + b) * D_ + n] = acc;
}

__global__ __launch_bounds__(256) void qproj_reduce(
    const float* __restrict__ ppart, const float* __restrict__ bq,
    float* __restrict__ q) {
  const int i = blockIdx.x * 256 + threadIdx.x;
  const int b = i >> 11, n = i & (D_ - 1);
  float acc = 0.f;
  for (int c = 0; c < PCH; ++c)
    acc += ppart[((long)c * B_ + b) * D_ + n];
  q[i] = acc + bq[n];
}

__global__ __launch_bounds__(256) void qt_kernel(
    const float* __restrict__ q, const float* __restrict__ Wkvu,
    const float* __restrict__ bkvu, float* __restrict__ qt,
    float* __restrict__ blog) {
  __shared__ float qh[DH_];
  __shared__ float red[DH_];
  const int h = blockIdx.x, b = blockIdx.y, t = threadIdx.x;
  if (t < DH_) qh[t] = q[b * D_ + h * DH_ + t];
  __syncthreads();
  for (int l = t; l < L_; l += 256) {
    const float* wr = Wkvu + (long)l * 4096 + h * DH_;
    float acc = 0.f;
    for (int d = 0; d < DH_; d += 4) {
      float4 w4 = *(const float4*)(wr + d);
      acc = fmaf(qh[d], w4.x, acc);
      acc = fmaf(qh[d + 1], w4.y, acc);
      acc = fmaf(qh[d + 2], w4.z, acc);
      acc = fmaf(qh[d + 3], w4.w, acc);
    }
    qt[((long)b * H_ + h) * L_ + l] = acc;
  }
  if (t < DH_) red[t] = qh[t] * bkvu[h * DH_ + t];
  __syncthreads();
  if (t == 0) {
    float s = 0.f;
    for (int i = 0; i < DH_; ++i) s += red[i];
    blog[b * H_ + h] = s;
  }
}

__global__ __launch_bounds__(256) void logits_kernel(
    const float* __restrict__ Kd, const int* __restrict__ rowmapExt,
    const float* __restrict__ qt, const float* __restrict__ blog,
    float* __restrict__ logits) {
  const int b = blockIdx.y;
  const int k = blockIdx.x * 16 + (threadIdx.x >> 4);
  const int h = threadIdx.x & 15;
  const float* kr = Kd + (long)rowmapExt[b * SLOTS + k] * L_;
  const float* qr = qt + ((long)b * H_ + h) * L_;
  float acc = 0.f;
  for (int l = 0; l < L_; l += 4) {
    float4 kv = *(const float4*)(kr + l);
    acc = fmaf(qr[l], kv.x, acc);
    acc = fmaf(qr[l + 1], kv.y, acc);
    acc = fmaf(qr[l + 2], kv.z, acc);
    acc = fmaf(qr[l + 3], kv.w, acc);
  }
  logits[((long)b * H_ + h) * SLOTS + k] =
      (acc + blog[b * H_ + h]) * 0.088388347648318447f;
}

__global__ __launch_bounds__(256) void softmax_kernel(
    float* __restrict__ logits, const float* __restrict__ multExt) {
  __shared__ float redf[4];
  __shared__ double redd[4];
  const int bh = blockIdx.x;
  const int b = bh >> 4;
  float* row = logits + (long)bh * SLOTS;
  const float* mult = multExt + b * SLOTS;
  const int t = threadIdx.x;
  const int wave = t >> 6, lane = t & 63;
  float m = -3.4e38f;
  for (int i = t; i < SLOTS; i += 256) m = fmaxf(m, row[i]);
#pragma unroll
  for (int off = 32; off >= 1; off >>= 1) m = fmaxf(m, __shfl_xor(m, off, 64));
  if (lane == 0) redf[wave] = m;
  __syncthreads();
  m = fmaxf(fmaxf(redf[0], redf[1]), fmaxf(redf[2], redf[3]));
  double s = 0.0;
  for (int i = t; i < SLOTS; i += 256) {
    float e = expf(row[i] - m) * mult[i];
    row[i] = e;
    s += (double)e;
  }
#pragma unroll
  for (int off = 32; off >= 1; off >>= 1) s += __shfl_xor(s, off, 64);
  if (lane == 0) redd[wave] = s;
  __syncthreads();
  const float inv = (float)(1.0 / (redd[0] + redd[1] + redd[2] + redd[3]));
  for (int i = t; i < SLOTS; i += 256) row[i] *= inv;
}

__global__ __launch_bounds__(256) void vt_part(
    const float* __restrict__ Vsel, const float* __restrict__ attn,
    float* __restrict__ vpart) {
  const int b = blockIdx.y, c = blockIdx.z;
  const int t = threadIdx.x;
  const int l = blockIdx.x * 64 + (t & 63);
  const int hg = t >> 6;
  float acc[4] = {0.f, 0.f, 0.f, 0.f};
  const float* ar = attn + (long)b * H_ * SLOTS;
  const int k0 = c * VCHK, k1 = k0 + VCHK;
  for (int k = k0; k < k1; ++k) {
    float v = Vsel[((long)b * SLOTS + k) * L_ + l];
#pragma unroll
    for (int a = 0; a < 4; ++a)
      acc[a] = fmaf(ar[(hg * 4 + a) * SLOTS + k], v, acc[a]);
  }
#pragma unroll
  for (int a = 0; a < 4; ++a)
    vpart[(((long)c * B_ + b) * H_ + hg * 4 + a) * L_ + l] = acc[a];
}

__global__ __launch_bounds__(256) void vt_reduce(
    const float* __restrict__ vpart, float* __restrict__ vt) {
  const int i = blockIdx.x * 256 + threadIdx.x;
  float acc = 0.f;
  for (int c = 0; c < VCH; ++c)
    acc += vpart[(long)c * (B_ * H_ * L_) + i];
  vt[i] = acc;
}

__global__ __launch_bounds__(512) void oproj_kernel(
    const float* __restrict__ vt, const float* __restrict__ Wkvu,
    const float* __restrict__ bkvu, float* __restrict__ o) {
  __shared__ float vs[L_];
  __shared__ float part[4][DH_];
  const int h = blockIdx.x, b = blockIdx.y, t = threadIdx.x;
  if (t < 128)
    ((float4*)vs)[t] = ((const float4*)(vt + ((long)b * H_ + h) * L_))[t];
  __syncthreads();
  const int lc = t >> 7;
  const int ct = t & 127;
  const int col = h * DH_ + ct;
  float acc = 0.f;
  const int l0 = lc * 128;
  for (int l = l0; l < l0 + 128; ++l)
    acc = fmaf(vs[l], Wkvu[(long)l * 4096 + 2048 + col], acc);
  part[lc][ct] = acc;
  __syncthreads();
  if (lc == 0)
    o[b * D_ + col] = ((part[0][ct] + part[1][ct]) + (part[2][ct] + part[3][ct]))
                      + bkvu[2048 + col];
}

__global__ __launch_bounds__(128) void out_part(
    const float* __restrict__ o, const float* __restrict__ Wout,
    float* __restrict__ opart) {
  __shared__ float os[PCHD];
  const int b = blockIdx.y, c = blockIdx.z, t = threadIdx.x;
  const int d0 = c * PCHD;
  const float* orr = o + (long)b * D_ + d0;
  os[t] = orr[t]; os[t + 128] = orr[t + 128];
  __syncthreads();
  const int n = blockIdx.x * 128 + t;
  float acc = 0.f;
  for (int dd = 0; dd < PCHD; ++dd)
    acc = fmaf(os[dd], Wout[(long)(d0 + dd) * D_ + n], acc);
  opart[((long)c * B_ + b) * D_ + n] = acc;
}

__global__ __launch_bounds__(256) void out_reduce(
    const float* __restrict__ opart, const float* __restrict__ bout,
    float* __restrict__ out) {
  const int i = blockIdx.x * 256 + threadIdx.x;
  const int b = i >> 11, n = i & (D_ - 1);
  float acc = 0.f;
  for (int c = 0; c < PCH; ++c)
    acc += opart[((long)c * B_ + b) * D_ + n];
  out[i] = acc + bout[n];
}

extern "C" void kernel_launch(void* const* d_in, const int* in_sizes, int n_in,
                              void* d_out, int out_size, void* d_ws, size_t ws_size,
                              hipStream_t stream) {
  const float* x    = (const float*)d_in[0];
  const float* Wq   = (const float*)d_in[1];
  const float* bq   = (const float*)d_in[2];
  const float* Wkvd = (const float*)d_in[3];
  const float* bkvd = (const float*)d_in[4];
  const float* Wqd  = (const float*)d_in[5];
  const float* bqd  = (const float*)d_in[6];
  const float* Wkvu = (const float*)d_in[7];
  const float* bkvu = (const float*)d_in[8];
  const float* Wo   = (const float*)d_in[9];
  const float* bo   = (const float*)d_in[10];
  float* out = (float*)d_out;

  char* p = (char*)d_ws;
  auto alloc = [&](size_t bytes) {
    char* r = p;
    p += (bytes + 255) & ~(size_t)255;
    return r;
  };
  float*  Kd       = (float*)alloc((size_t)B_ * S_ * L_ * 4);       // 134.2 MB
  ushort* Kq8      = (ushort*)alloc((size_t)B_ * S_ * L_ * 2);      // 67.1 MB
  float*  Vsel     = (float*)alloc((size_t)B_ * SLOTS * L_ * 4);    // 34.6 MB
  ushort* Wsp      = (ushort*)alloc((size_t)2 * 64 * 4 * 1024 * 8 * 2);  // 8.4 MB
  float*  WT       = (float*)alloc((size_t)L_ * D_ * 4);            // 4 MB
  ushort* Wq8      = (ushort*)alloc((size_t)D_ * L_ * 2);           // 2 MB
  double* qpart    = (double*)alloc((size_t)B_ * QCH * L_ * 8);     // 1 MB
  float*  ppart    = (float*)alloc((size_t)PCH * B_ * D_ * 4);
  float*  opart    = (float*)alloc((size_t)PCH * B_ * D_ * 4);
  float*  vpart    = (float*)alloc((size_t)VCH * B_ * H_ * L_ * 4);
  float*  scores   = (float*)alloc((size_t)B_ * S_ * 4);
  float*  qidx     = (float*)alloc((size_t)B_ * L_ * 4);
  int*    rowmap   = (int*)alloc((size_t)B_ * TOPK_ * 4);
  int*    rowmapE  = (int*)alloc((size_t)B_ * SLOTS * 4);
  float*  multE    = (float*)alloc((size_t)B_ * SLOTS * 4);
  float*  vstarF   = (float*)alloc((size_t)B_ * 4);
  int*    wideL    = (int*)alloc((size_t)RCAPW * 4);                // 2 MB
  int2*   narrowL  = (int2*)alloc((size_t)NCAP * 8);                // 0.5 MB
  int*    wideCnt  = (int*)alloc(256);
  int*    narrowCnt= (int*)alloc(256);
  int*    flagArr  = (int*)alloc((size_t)B_ * S_ * 4);
  int*    extraR   = (int*)alloc((size_t)B_ * EXTCAP * 4);
  int*    extraCnt = (int*)alloc((size_t)B_ * 4);
  int*    cntI2O   = (int*)alloc((size_t)B_ * 4);
  float*  qv       = (float*)alloc((size_t)B_ * D_ * 4);
  float*  qt       = (float*)alloc((size_t)B_ * H_ * L_ * 4);
  float*  blog     = (float*)alloc((size_t)B_ * H_ * 4);
  float*  logits   = (float*)alloc((size_t)B_ * H_ * SLOTS * 4);
  float*  vt       = (float*)alloc((size_t)B_ * H_ * L_ * 4);
  float*  ov       = (float*)alloc((size_t)B_ * D_ * 4);
  (void)ws_size; (void)in_sizes; (void)n_in; (void)out_size;

  zero_kernel<<<(B_ * S_ + 255) / 256, 256, 0, stream>>>(flagArr, wideCnt, narrowCnt, extraCnt, cntI2O);
  // one-shot weight preprocessing
  wsplit_kernel<<<dim3(4, 64), 256, 0, stream>>>(Wkvd, Wsp);
  wtrans_kernel<<<dim3(D_ / 256, L_), 256, 0, stream>>>(Wkvd, WT);
  wq8_kernel<<<(D_ * L_ / 4) / 256, 256, 0, stream>>>(Wqd, Wq8);
  // K_down via 3-term bf16-split MFMA (2 halves, XCD-swizzled) + LDS-buffered flags
  gemm_mfma<true><<<1024, 256, 0, stream>>>(
      x, Wsp, 0, 0, bkvd, Kd, Kq8, nullptr, wideL, wideCnt);
  gemm_mfma<true><<<1024, 256, 0, stream>>>(
      x, Wsp, 0, 256, bkvd, Kd, Kq8, nullptr, wideL, wideCnt);
  // exact fixup of midpoint-adjacent cells -> Kq8 exact-grade + narrow records
  fixup_kernel<<<8192, 256, 0, stream>>>(wideL, wideCnt, x, WT, bkvd, Kq8, narrowL, narrowCnt);
  // selection path
  qidx_part<<<dim3(QCH, B_), 256, 0, stream>>>(x, Wq8, qpart);
  qidx_reduce<<<(B_ * L_) / 256, 256, 0, stream>>>(qpart, bqd, qidx);
  scores_kernel<<<(B_ * S_) / 4, 256, 0, stream>>>(Kq8, qidx, scores);
  topk_kernel<<<B_, 256, 0, stream>>>(scores, rowmap, vstarF);
  risky_eval<<<NCAP / 256, 256, 0, stream>>>(narrowL, narrowCnt, Kq8, qidx, scores, vstarF,
                                             flagArr, extraR, extraCnt, cntI2O);
  counterparty_kernel<<<B_, 256, 0, stream>>>(scores, rowmap, vstarF, flagArr, extraR, extraCnt, cntI2O);
  buildext_kernel<<<dim3((SLOTS + 255) / 256, B_), 256, 0, stream>>>(rowmap, extraR, extraCnt, flagArr, rowmapE, multE);
  // V_down at selected+hedged rows (3-term, value-grade), 528 blocks
  gemm_mfma<false><<<528, 256, 0, stream>>>(
      x, Wsp, 512, 0, bkvd + 512, Vsel, nullptr, rowmapE, nullptr, nullptr);
  // attention (up-projections folded), parallelized value path
  qproj_part<<<dim3(D_ / 128, B_, PCH), 128, 0, stream>>>(x, Wq, ppart);
  qproj_reduce<<<(B_ * D_) / 256, 256, 0, stream>>>(ppart, bq, qv);
  qt_kernel<<<dim3(H_, B_), 256, 0, stream>>>(qv, Wkvu, bkvu, qt, blog);
  logits_kernel<<<dim3(SLOTS / 16, B_), 256, 0, stream>>>(Kd, rowmapE, qt, blog, logits);
  softmax_kernel<<<B_ * H_, 256, 0, stream>>>(logits, multE);
  vt_part<<<dim3(L_ / 64, B_, VCH), 256, 0, stream>>>(Vsel, logits, vpart);
  vt_reduce<<<(B_ * H_ * L_) / 256, 256, 0, stream>>>(vpart, vt);
  oproj_kernel<<<dim3(H_, B_), 512, 0, stream>>>(vt, Wkvu, bkvu, ov);
  out_part<<<dim3(D_ / 128, B_, PCH), 128, 0, stream>>>(ov, Wo, opart);
  out_reduce<<<(B_ * D_) / 256, 256, 0, stream>>>(opart, bo, out);
}